// Round 6
// baseline (226.880 us; speedup 1.0000x reference)
//
#include <hip/hip_runtime.h>
#include <stdint.h>

typedef unsigned short u16;
typedef __attribute__((ext_vector_type(8))) __bf16 bf16x8;
typedef __attribute__((ext_vector_type(4))) float f32x4;

#define Dn 512
#define Mn 16384  // T*B rows

// ---------- helpers ----------

__device__ __forceinline__ u16 f2bf(float f) {
  unsigned u = __float_as_uint(f);
  u += 0x7fffu + ((u >> 16) & 1u);
  return (u16)(u >> 16);
}

__device__ __forceinline__ float bf2f(u16 b) {
  return __uint_as_float(((unsigned)b) << 16);
}

__device__ __forceinline__ void async16(const u16* g, u16* l) {
  // global -> LDS direct copy, 16 B per lane. LDS dest = wave-uniform base + lane*16.
  __builtin_amdgcn_global_load_lds(
      (const __attribute__((address_space(1))) unsigned int*)g,
      (__attribute__((address_space(3))) unsigned int*)l, 16, 0, 0);
}

__device__ __forceinline__ float sigmoidf_(float v) {
  return 1.f / (1.f + __expf(-v));
}

// ---------- merged cast kernel ----------
__global__ void cast_all(const float* __restrict__ y, const float* __restrict__ x,
                         const float* w0, const float* w1, const float* w2,
                         const float* w3, const float* w4, const float* w5,
                         u16* __restrict__ yb, u16* __restrict__ xb,
                         u16* __restrict__ wb) {
  int b = blockIdx.x;
  const float* src;
  u16* dst;
  if (b < 8192) {
    src = y; dst = yb;
  } else if (b < 16384) {
    src = x; dst = xb; b -= 8192;
  } else {
    b -= 16384;
    const int wi = b >> 8;
    b &= 255;
    src = wi == 0 ? w0 : wi == 1 ? w1 : wi == 2 ? w2 : wi == 3 ? w3 : wi == 4 ? w4 : w5;
    dst = wb + wi * 262144;
  }
  const int i4 = b * 256 + (int)threadIdx.x;
  float4 v = ((const float4*)src)[i4];
  ushort4 o;
  o.x = f2bf(v.x); o.y = f2bf(v.y); o.z = f2bf(v.z); o.w = f2bf(v.w);
  ((ushort4*)dst)[i4] = o;
}

// ---------- fused r/z GEMM: 128x64 tile, BK=32, 32 KB LDS, 4 blocks/CU ----------
// accR = y@Wr^T + x@Ur^T ; accZ = y@Wz^T + x@Uz^T
// grid: (16384/128)*(512/64) = 1024 blocks, 256 threads (4 waves, 2x2, wave tile 64x32).
// XOR swizzle (proven 0-conflict in round 5): row r's logical 16B chunk c at phys c^((r>>1)&3).
__global__ __launch_bounds__(256, 4) void gemm_rz(
    const u16* __restrict__ yb, const u16* __restrict__ xb,
    const u16* __restrict__ wb,  // [Wr,Ur,Wz,Uz] each 512*512 bf16
    const float* __restrict__ bg,
    u16* __restrict__ rxb, u16* __restrict__ zb) {
  __shared__ u16 smem[16384];  // 32 KB: sY 4096 | sX 4096 | sW 4*2048 (u16 units)
  u16* sY = smem;
  u16* sX = smem + 4096;
  u16* sW = smem + 8192;

  const int tid = threadIdx.x;
  const int lane = tid & 63;
  const int wave = tid >> 6;
  const int waveM = wave >> 1, waveN = wave & 1;
  const int nb = blockIdx.x & 7, mb = blockIdx.x >> 3;
  const int rowStart = mb * 128, colStart = nb * 64;
  const int wbyte = (tid & 192) * 16;  // wave * 1024 B
  const int lm = lane & 15, quad = lane >> 4;

  // staging map: row = tid>>2 (0..63 per slab), phys chunk = tid&3,
  // logical chunk = (tid&3) ^ ((row>>1)&3) = (tid&3) ^ ((tid>>3)&3)
  const int srow = tid >> 2;
  const int scol = (((tid & 3) ^ ((tid >> 3) & 3)) * 8);
  // fragment read phys chunk: quad ^ ((lm>>1)&3)
  const int aswz = (quad ^ ((lm >> 1) & 3)) * 8;

  f32x4 accR[4][2] = {};
  f32x4 accZ[4][2] = {};

  for (int k0 = 0; k0 < Dn; k0 += 32) {
#pragma unroll
    for (int s = 0; s < 2; ++s) {
      async16(yb + (size_t)(rowStart + s * 64 + srow) * Dn + k0 + scol,
              (u16*)((char*)sY + s * 4096 + wbyte));
      async16(xb + (size_t)(rowStart + s * 64 + srow) * Dn + k0 + scol,
              (u16*)((char*)sX + s * 4096 + wbyte));
    }
#pragma unroll
    for (int w = 0; w < 4; ++w)
      async16(wb + (size_t)w * 262144 + (size_t)(colStart + srow) * Dn + k0 + scol,
              (u16*)((char*)sW + w * 4096 + wbyte));
    __syncthreads();

    bf16x8 ay[4], ax[4], bw[2];
#pragma unroll
    for (int i = 0; i < 4; ++i) {
      const int off = (waveM * 64 + i * 16 + lm) * 32 + aswz;
      ay[i] = *(const bf16x8*)(sY + off);
      ax[i] = *(const bf16x8*)(sX + off);
    }
    // Wr (ay -> accR)
#pragma unroll
    for (int j = 0; j < 2; ++j)
      bw[j] = *(const bf16x8*)(sW + 0 * 2048 + (waveN * 32 + j * 16 + lm) * 32 + aswz);
#pragma unroll
    for (int i = 0; i < 4; ++i)
#pragma unroll
      for (int j = 0; j < 2; ++j)
        accR[i][j] = __builtin_amdgcn_mfma_f32_16x16x32_bf16(ay[i], bw[j], accR[i][j], 0, 0, 0);
    // Ur (ax -> accR)
#pragma unroll
    for (int j = 0; j < 2; ++j)
      bw[j] = *(const bf16x8*)(sW + 1 * 2048 + (waveN * 32 + j * 16 + lm) * 32 + aswz);
#pragma unroll
    for (int i = 0; i < 4; ++i)
#pragma unroll
      for (int j = 0; j < 2; ++j)
        accR[i][j] = __builtin_amdgcn_mfma_f32_16x16x32_bf16(ax[i], bw[j], accR[i][j], 0, 0, 0);
    // Wz (ay -> accZ)
#pragma unroll
    for (int j = 0; j < 2; ++j)
      bw[j] = *(const bf16x8*)(sW + 2 * 2048 + (waveN * 32 + j * 16 + lm) * 32 + aswz);
#pragma unroll
    for (int i = 0; i < 4; ++i)
#pragma unroll
      for (int j = 0; j < 2; ++j)
        accZ[i][j] = __builtin_amdgcn_mfma_f32_16x16x32_bf16(ay[i], bw[j], accZ[i][j], 0, 0, 0);
    // Uz (ax -> accZ)
#pragma unroll
    for (int j = 0; j < 2; ++j)
      bw[j] = *(const bf16x8*)(sW + 3 * 2048 + (waveN * 32 + j * 16 + lm) * 32 + aswz);
#pragma unroll
    for (int i = 0; i < 4; ++i)
#pragma unroll
      for (int j = 0; j < 2; ++j)
        accZ[i][j] = __builtin_amdgcn_mfma_f32_16x16x32_bf16(ax[i], bw[j], accZ[i][j], 0, 0, 0);
    __syncthreads();
  }

  // epilogue: rx = bf16(sigmoid(accR) * x); z = bf16(sigmoid(accZ - bg))
#pragma unroll
  for (int j = 0; j < 2; ++j) {
    const int e = colStart + waveN * 32 + j * 16 + lm;
    const float bgv = bg[e];
#pragma unroll
    for (int i = 0; i < 4; ++i) {
      const int m0 = rowStart + waveM * 64 + i * 16 + quad * 4;
#pragma unroll
      for (int rg = 0; rg < 4; ++rg) {
        const size_t idx = (size_t)(m0 + rg) * Dn + e;
        const float r = sigmoidf_(accR[i][j][rg]);
        rxb[idx] = f2bf(r * bf2f(xb[idx]));
        zb[idx] = f2bf(sigmoidf_(accZ[i][j][rg] - bgv));
      }
    }
  }
}

// ---------- final GEMM: accF = y@Wg^T + rx@Ug^T (K=1024); 128x64, BK=64, 24 KB LDS ----------
// grid 1024. Swizzle: row r's logical chunk c (0..7) at phys chunk c ^ (r&7).
__global__ __launch_bounds__(256, 4) void gemm_gu(
    const u16* __restrict__ yb, const u16* __restrict__ rxb,
    const u16* __restrict__ wg,  // Wg at +0, Ug at +262144
    const u16* __restrict__ zb, const u16* __restrict__ xb,
    float* __restrict__ out) {
  __shared__ u16 smem[12288];  // 24 KB: sA 8192 | sB 4096 (u16 units)
  u16* sA = smem;
  u16* sB = smem + 8192;

  const int tid = threadIdx.x;
  const int lane = tid & 63;
  const int wave = tid >> 6;
  const int waveM = wave >> 1, waveN = wave & 1;
  const int nb = blockIdx.x & 7, mb = blockIdx.x >> 3;
  const int rowStart = mb * 128, colStart = nb * 64;
  const int wbyte = (tid & 192) * 16;
  const int lm = lane & 15, quad = lane >> 4;

  const int srow = tid >> 3;                              // 0..31 per slab
  const int scol = (((tid & 7) ^ ((tid >> 3) & 7)) * 8);  // logical chunk * 8
  const int lswz = lm & 7;                                // read-side row swizzle

  f32x4 acc[4][2] = {};

  for (int kq = 0; kq < 16; ++kq) {
    const int half = kq >> 3;
    const int k0 = (kq & 7) * 64;
    const u16* abase = half ? rxb : yb;
    const u16* wbase = wg + (size_t)half * 262144;
#pragma unroll
    for (int s = 0; s < 4; ++s)
      async16(abase + (size_t)(rowStart + s * 32 + srow) * Dn + k0 + scol,
              (u16*)((char*)sA + s * 4096 + wbyte));
#pragma unroll
    for (int s = 0; s < 2; ++s)
      async16(wbase + (size_t)(colStart + s * 32 + srow) * Dn + k0 + scol,
              (u16*)((char*)sB + s * 4096 + wbyte));
    __syncthreads();

#pragma unroll
    for (int kk = 0; kk < 2; ++kk) {
      bf16x8 aa[4], bw[2];
#pragma unroll
      for (int i = 0; i < 4; ++i)
        aa[i] = *(const bf16x8*)(sA + (waveM * 64 + i * 16 + lm) * 64 +
                                 ((kk * 4 + quad) ^ lswz) * 8);
#pragma unroll
      for (int j = 0; j < 2; ++j)
        bw[j] = *(const bf16x8*)(sB + (waveN * 32 + j * 16 + lm) * 64 +
                                 ((kk * 4 + quad) ^ lswz) * 8);
#pragma unroll
      for (int i = 0; i < 4; ++i)
#pragma unroll
        for (int j = 0; j < 2; ++j)
          acc[i][j] = __builtin_amdgcn_mfma_f32_16x16x32_bf16(aa[i], bw[j], acc[i][j], 0, 0, 0);
    }
    __syncthreads();
  }

  // epilogue: out = (1-z)x + z*tanh(accF)
#pragma unroll
  for (int j = 0; j < 2; ++j) {
    const int e = colStart + waveN * 32 + j * 16 + lm;
#pragma unroll
    for (int i = 0; i < 4; ++i) {
      const int m0 = rowStart + waveM * 64 + i * 16 + quad * 4;
#pragma unroll
      for (int rg = 0; rg < 4; ++rg) {
        const size_t idx = (size_t)(m0 + rg) * Dn + e;
        const float pre = acc[i][j][rg];
        const float ex = __expf(-2.f * pre);
        const float h = (1.f - ex) / (1.f + ex);  // tanh
        const float z = bf2f(zb[idx]);
        const float xv = bf2f(xb[idx]);
        out[idx] = (1.f - z) * xv + z * h;
      }
    }
  }
}

// ---------- launch ----------
extern "C" void kernel_launch(void* const* d_in, const int* in_sizes, int n_in,
                              void* d_out, int out_size, void* d_ws, size_t ws_size,
                              hipStream_t stream) {
  const float* x  = (const float*)d_in[0];
  const float* y  = (const float*)d_in[1];
  const float* Wr = (const float*)d_in[2];
  const float* Ur = (const float*)d_in[3];
  const float* Wz = (const float*)d_in[4];
  const float* Uz = (const float*)d_in[5];
  const float* Wg = (const float*)d_in[6];
  const float* Ug = (const float*)d_in[7];
  const float* bg = (const float*)d_in[8];
  float* out = (float*)d_out;

  // ws layout (bytes): yb 16M | xb 16M | rxb 16M | wb 3M | zb 16M  => 67 MB
  char* ws = (char*)d_ws;
  u16* yb  = (u16*)(ws);
  u16* xb  = (u16*)(ws + 16777216);
  u16* rxb = (u16*)(ws + 2 * 16777216);
  u16* wb  = (u16*)(ws + 3 * 16777216);           // 6 * 512*512 bf16
  u16* zb  = (u16*)(ws + 3 * 16777216 + 3145728);

  cast_all<<<17920, 256, 0, stream>>>(y, x, Wr, Ur, Wz, Uz, Wg, Ug, yb, xb, wb);
  gemm_rz<<<1024, 256, 0, stream>>>(yb, xb, wb, bg, rxb, zb);
  gemm_gu<<<1024, 256, 0, stream>>>(yb, rxb, wb + (size_t)4 * 262144, zb, xb, out);
}

// Round 7
// 226.788 us; speedup vs baseline: 1.0004x; 1.0004x over previous
//
#include <hip/hip_runtime.h>
#include <stdint.h>

typedef unsigned short u16;
typedef __attribute__((ext_vector_type(8))) __bf16 bf16x8;
typedef __attribute__((ext_vector_type(4))) float f32x4;

#define Dn 512
#define Mn 16384  // T*B rows

// ---------- helpers ----------

__device__ __forceinline__ u16 f2bf(float f) {
  unsigned u = __float_as_uint(f);
  u += 0x7fffu + ((u >> 16) & 1u);
  return (u16)(u >> 16);
}

__device__ __forceinline__ float bf2f(u16 b) {
  return __uint_as_float(((unsigned)b) << 16);
}

__device__ __forceinline__ void async16(const u16* g, u16* l) {
  // global -> LDS direct copy, 16 B per lane. LDS dest = wave-uniform base + lane*16.
  __builtin_amdgcn_global_load_lds(
      (const __attribute__((address_space(1))) unsigned int*)g,
      (__attribute__((address_space(3))) unsigned int*)l, 16, 0, 0);
}

__device__ __forceinline__ float sigmoidf_(float v) {
  return 1.f / (1.f + __expf(-v));
}

// ---------- merged cast kernel ----------
// blocks 0..8191: y -> yb ; 8192..16383: x -> xb ;
// 16384..17919: 6 weights -> concat layouts:
//   bRZ (1024 x 1024 bf16): rows 0-511 = [Wr | Ur], rows 512-1023 = [Wz | Uz]
//   bG  ( 512 x 1024 bf16): rows 0-511 = [Wg | Ug]
__global__ void cast_all(const float* __restrict__ y, const float* __restrict__ x,
                         const float* w0, const float* w1, const float* w2,
                         const float* w3, const float* w4, const float* w5,
                         u16* __restrict__ yb, u16* __restrict__ xb,
                         u16* __restrict__ bRZ, u16* __restrict__ bG) {
  int b = blockIdx.x;
  const int t = (int)threadIdx.x;
  if (b < 16384) {
    const float* src;
    u16* dst;
    if (b < 8192) { src = y; dst = yb; }
    else          { src = x; dst = xb; b -= 8192; }
    const int i4 = b * 256 + t;
    float4 v = ((const float4*)src)[i4];
    ushort4 o;
    o.x = f2bf(v.x); o.y = f2bf(v.y); o.z = f2bf(v.z); o.w = f2bf(v.w);
    ((ushort4*)dst)[i4] = o;
    return;
  }
  b -= 16384;
  const int wi = b >> 8;  // 0..5 : Wr,Ur,Wz,Uz,Wg,Ug
  const int bb = b & 255;
  const float* src = wi == 0 ? w0 : wi == 1 ? w1 : wi == 2 ? w2
                   : wi == 3 ? w3 : wi == 4 ? w4 : w5;
  const int i4 = bb * 256 + t;        // float4 index within 512x512 weight
  const int e  = i4 >> 7;             // output row 0..511
  const int c4 = i4 & 127;            // float4 col within 512
  float4 v = ((const float4*)src)[i4];
  ushort4 o;
  o.x = f2bf(v.x); o.y = f2bf(v.y); o.z = f2bf(v.z); o.w = f2bf(v.w);
  ushort4* base = (wi >= 4) ? (ushort4*)bG : (ushort4*)bRZ;
  const int row = e + ((wi == 2 || wi == 3) ? 512 : 0);
  const int off = row * 256 + c4 + ((wi & 1) ? 128 : 0);  // 256 ushort4 per 1024-col row
  base[off] = o;
}

// ---------- GEMM 1: C = [y|x] @ bRZ^T  (M=16384, N=1024, K=1024) ----------
// 128x128 tile, BK=64, 32 KB LDS, grid 128*8 = 1024 blocks, 4 waves (2x2), wave 64x64.
// nb = blockIdx&7 so same-B blocks share an XCD (round-robin dispatch heuristic).
// XOR swizzle (0-conflict, proven r5/r6): row r logical chunk c at phys c^(r&7).
// Epilogue: nb 0-3 -> rx = bf16(sigmoid(acc)*x); nb 4-7 -> z = bf16(sigmoid(acc-bg)).
__global__ __launch_bounds__(256, 4) void gemm_rz1(
    const u16* __restrict__ yb, const u16* __restrict__ xb,
    const u16* __restrict__ bRZ, const float* __restrict__ bg,
    u16* __restrict__ rxb, u16* __restrict__ zb) {
  __shared__ u16 smem[16384];  // sA 8192 | sB 8192 (u16), 32 KB
  u16* sA = smem;
  u16* sB = smem + 8192;

  const int tid = threadIdx.x;
  const int lane = tid & 63;
  const int wave = tid >> 6;
  const int waveM = wave >> 1, waveN = wave & 1;
  const int nb = blockIdx.x & 7, mb = blockIdx.x >> 3;
  const int rowStart = mb * 128, colStart = nb * 128;
  const int wbyte = (tid & 192) * 16;
  const int lm = lane & 15, quad = lane >> 4;

  const int srow = tid >> 3;                              // 0..31 per slab
  const int scol = (((tid & 7) ^ ((tid >> 3) & 7)) * 8);  // logical chunk * 8 elems
  const int lswz = lm & 7;

  f32x4 acc[4][4] = {};

  for (int kq = 0; kq < 16; ++kq) {
    const int half = kq >> 3;
    const int k0 = (kq & 7) * 64;
    const u16* abase = half ? xb : yb;  // A = [y | x] along K
#pragma unroll
    for (int s = 0; s < 4; ++s) {
      async16(abase + (size_t)(rowStart + s * 32 + srow) * 512 + k0 + scol,
              (u16*)((char*)sA + s * 4096 + wbyte));
      async16(bRZ + (size_t)(colStart + s * 32 + srow) * 1024 + kq * 64 + scol,
              (u16*)((char*)sB + s * 4096 + wbyte));
    }
    __syncthreads();

#pragma unroll
    for (int kk = 0; kk < 2; ++kk) {
      bf16x8 aa[4], bw[4];
#pragma unroll
      for (int i = 0; i < 4; ++i)
        aa[i] = *(const bf16x8*)(sA + (waveM * 64 + i * 16 + lm) * 64 +
                                 ((kk * 4 + quad) ^ lswz) * 8);
#pragma unroll
      for (int j = 0; j < 4; ++j)
        bw[j] = *(const bf16x8*)(sB + (waveN * 64 + j * 16 + lm) * 64 +
                                 ((kk * 4 + quad) ^ lswz) * 8);
#pragma unroll
      for (int i = 0; i < 4; ++i)
#pragma unroll
        for (int j = 0; j < 4; ++j)
          acc[i][j] = __builtin_amdgcn_mfma_f32_16x16x32_bf16(aa[i], bw[j], acc[i][j], 0, 0, 0);
    }
    __syncthreads();
  }

  if (colStart < 512) {
    // R half: rx = bf16(sigmoid(acc) * x)
#pragma unroll
    for (int j = 0; j < 4; ++j) {
      const int e = colStart + waveN * 64 + j * 16 + lm;
#pragma unroll
      for (int i = 0; i < 4; ++i) {
        const int m0 = rowStart + waveM * 64 + i * 16 + quad * 4;
#pragma unroll
        for (int rg = 0; rg < 4; ++rg) {
          const size_t idx = (size_t)(m0 + rg) * 512 + e;
          const float r = sigmoidf_(acc[i][j][rg]);
          rxb[idx] = f2bf(r * bf2f(xb[idx]));
        }
      }
    }
  } else {
    // Z half: z = bf16(sigmoid(acc - bg))
#pragma unroll
    for (int j = 0; j < 4; ++j) {
      const int e = colStart - 512 + waveN * 64 + j * 16 + lm;
      const float bgv = bg[e];
#pragma unroll
      for (int i = 0; i < 4; ++i) {
        const int m0 = rowStart + waveM * 64 + i * 16 + quad * 4;
#pragma unroll
        for (int rg = 0; rg < 4; ++rg) {
          const size_t idx = (size_t)(m0 + rg) * 512 + e;
          zb[idx] = f2bf(sigmoidf_(acc[i][j][rg] - bgv));
        }
      }
    }
  }
}

// ---------- GEMM 2: accF = [y|rx] @ bG^T (M=16384, N=512, K=1024) ----------
// Same 128x128/BK=64 structure. grid 128*4 = 512 blocks.
// Epilogue: out = (1-z)x + z*tanh(accF)
__global__ __launch_bounds__(256, 4) void gemm_gu1(
    const u16* __restrict__ yb, const u16* __restrict__ rxb,
    const u16* __restrict__ bG,
    const u16* __restrict__ zb, const u16* __restrict__ xb,
    float* __restrict__ out) {
  __shared__ u16 smem[16384];
  u16* sA = smem;
  u16* sB = smem + 8192;

  const int tid = threadIdx.x;
  const int lane = tid & 63;
  const int wave = tid >> 6;
  const int waveM = wave >> 1, waveN = wave & 1;
  const int nb = blockIdx.x & 3, mb = blockIdx.x >> 2;
  const int rowStart = mb * 128, colStart = nb * 128;
  const int wbyte = (tid & 192) * 16;
  const int lm = lane & 15, quad = lane >> 4;

  const int srow = tid >> 3;
  const int scol = (((tid & 7) ^ ((tid >> 3) & 7)) * 8);
  const int lswz = lm & 7;

  f32x4 acc[4][4] = {};

  for (int kq = 0; kq < 16; ++kq) {
    const int half = kq >> 3;
    const int k0 = (kq & 7) * 64;
    const u16* abase = half ? rxb : yb;  // A = [y | rx] along K
#pragma unroll
    for (int s = 0; s < 4; ++s) {
      async16(abase + (size_t)(rowStart + s * 32 + srow) * 512 + k0 + scol,
              (u16*)((char*)sA + s * 4096 + wbyte));
      async16(bG + (size_t)(colStart + s * 32 + srow) * 1024 + kq * 64 + scol,
              (u16*)((char*)sB + s * 4096 + wbyte));
    }
    __syncthreads();

#pragma unroll
    for (int kk = 0; kk < 2; ++kk) {
      bf16x8 aa[4], bw[4];
#pragma unroll
      for (int i = 0; i < 4; ++i)
        aa[i] = *(const bf16x8*)(sA + (waveM * 64 + i * 16 + lm) * 64 +
                                 ((kk * 4 + quad) ^ lswz) * 8);
#pragma unroll
      for (int j = 0; j < 4; ++j)
        bw[j] = *(const bf16x8*)(sB + (waveN * 64 + j * 16 + lm) * 64 +
                                 ((kk * 4 + quad) ^ lswz) * 8);
#pragma unroll
      for (int i = 0; i < 4; ++i)
#pragma unroll
        for (int j = 0; j < 4; ++j)
          acc[i][j] = __builtin_amdgcn_mfma_f32_16x16x32_bf16(aa[i], bw[j], acc[i][j], 0, 0, 0);
    }
    __syncthreads();
  }

  // epilogue: out = (1-z)x + z*tanh(accF)
#pragma unroll
  for (int j = 0; j < 4; ++j) {
    const int e = colStart + waveN * 64 + j * 16 + lm;
#pragma unroll
    for (int i = 0; i < 4; ++i) {
      const int m0 = rowStart + waveM * 64 + i * 16 + quad * 4;
#pragma unroll
      for (int rg = 0; rg < 4; ++rg) {
        const size_t idx = (size_t)(m0 + rg) * 512 + e;
        const float pre = acc[i][j][rg];
        const float ex = __expf(-2.f * pre);
        const float h = (1.f - ex) / (1.f + ex);  // tanh
        const float z = bf2f(zb[idx]);
        const float xv = bf2f(xb[idx]);
        out[idx] = (1.f - z) * xv + z * h;
      }
    }
  }
}

// ---------- launch ----------
extern "C" void kernel_launch(void* const* d_in, const int* in_sizes, int n_in,
                              void* d_out, int out_size, void* d_ws, size_t ws_size,
                              hipStream_t stream) {
  const float* x  = (const float*)d_in[0];
  const float* y  = (const float*)d_in[1];
  const float* Wr = (const float*)d_in[2];
  const float* Ur = (const float*)d_in[3];
  const float* Wz = (const float*)d_in[4];
  const float* Uz = (const float*)d_in[5];
  const float* Wg = (const float*)d_in[6];
  const float* Ug = (const float*)d_in[7];
  const float* bg = (const float*)d_in[8];
  float* out = (float*)d_out;

  // ws layout (bytes): yb 16M | xb 16M | rxb 16M | zb 16M | bRZ 2M | bG 1M = 67 MB
  char* ws = (char*)d_ws;
  u16* yb  = (u16*)(ws);
  u16* xb  = (u16*)(ws + 16777216);
  u16* rxb = (u16*)(ws + 2 * 16777216);
  u16* zb  = (u16*)(ws + 3 * 16777216);
  u16* bRZ = (u16*)(ws + 4 * 16777216);
  u16* bG  = (u16*)(ws + 4 * 16777216 + 2097152);

  cast_all<<<17920, 256, 0, stream>>>(y, x, Wr, Ur, Wz, Uz, Wg, Ug, yb, xb, bRZ, bG);
  gemm_rz1<<<1024, 256, 0, stream>>>(yb, xb, bRZ, bg, rxb, zb);
  gemm_gu1<<<512, 256, 0, stream>>>(yb, rxb, bG, zb, xb, out);
}

// Round 8
// 202.160 us; speedup vs baseline: 1.1223x; 1.1218x over previous
//
#include <hip/hip_runtime.h>
#include <stdint.h>

typedef unsigned short u16;
typedef __attribute__((ext_vector_type(8))) __bf16 bf16x8;
typedef __attribute__((ext_vector_type(4))) float f32x4;

#define Dn 512
#define Mn 16384  // T*B rows

// ---------- helpers ----------

__device__ __forceinline__ u16 f2bf(float f) {
  unsigned u = __float_as_uint(f);
  u += 0x7fffu + ((u >> 16) & 1u);
  return (u16)(u >> 16);
}

__device__ __forceinline__ float bf2f(u16 b) {
  return __uint_as_float(((unsigned)b) << 16);
}

__device__ __forceinline__ void async16(const u16* g, u16* l) {
  // global -> LDS direct copy, 16 B per lane. LDS dest = wave-uniform base + lane*16.
  __builtin_amdgcn_global_load_lds(
      (const __attribute__((address_space(1))) unsigned int*)g,
      (__attribute__((address_space(3))) unsigned int*)l, 16, 0, 0);
}

__device__ __forceinline__ float sigmoidf_(float v) {
  return 1.f / (1.f + __expf(-v));
}

// ---------- merged cast kernel ----------
// blocks 0..8191: y -> yb ; 8192..16383: x -> xb ;
// 16384..17919: 6 weights -> concat layouts:
//   bRZ (1024 x 1024 bf16): rows 0-511 = [Wr | Ur], rows 512-1023 = [Wz | Uz]
//   bG  ( 512 x 1024 bf16): rows 0-511 = [Wg | Ug]
__global__ void cast_all(const float* __restrict__ y, const float* __restrict__ x,
                         const float* w0, const float* w1, const float* w2,
                         const float* w3, const float* w4, const float* w5,
                         u16* __restrict__ yb, u16* __restrict__ xb,
                         u16* __restrict__ bRZ, u16* __restrict__ bG) {
  int b = blockIdx.x;
  const int t = (int)threadIdx.x;
  if (b < 16384) {
    const float* src;
    u16* dst;
    if (b < 8192) { src = y; dst = yb; }
    else          { src = x; dst = xb; b -= 8192; }
    const int i4 = b * 256 + t;
    float4 v = ((const float4*)src)[i4];
    ushort4 o;
    o.x = f2bf(v.x); o.y = f2bf(v.y); o.z = f2bf(v.z); o.w = f2bf(v.w);
    ((ushort4*)dst)[i4] = o;
    return;
  }
  b -= 16384;
  const int wi = b >> 8;  // 0..5 : Wr,Ur,Wz,Uz,Wg,Ug
  const int bb = b & 255;
  const float* src = wi == 0 ? w0 : wi == 1 ? w1 : wi == 2 ? w2
                   : wi == 3 ? w3 : wi == 4 ? w4 : w5;
  const int i4 = bb * 256 + t;        // float4 index within 512x512 weight
  const int e  = i4 >> 7;             // output row 0..511
  const int c4 = i4 & 127;            // float4 col within 512
  float4 v = ((const float4*)src)[i4];
  ushort4 o;
  o.x = f2bf(v.x); o.y = f2bf(v.y); o.z = f2bf(v.z); o.w = f2bf(v.w);
  ushort4* base = (wi >= 4) ? (ushort4*)bG : (ushort4*)bRZ;
  const int row = e + ((wi == 2 || wi == 3) ? 512 : 0);
  const int off = row * 256 + c4 + ((wi & 1) ? 128 : 0);  // 256 ushort4 per 1024-col row
  base[off] = o;
}

// ---------- GEMM 1: C = [y|x] @ bRZ^T  (M=16384, N=1024, K=1024) ----------
// 128x128 tile, BK=64, 32 KB LDS, grid 1024, 4 waves (2x2), wave 64x64.
// XCD-aware ordering: mb = blockIdx&127 (fast), nb = blockIdx>>7. Since 128%8==0,
// all 8 blocks sharing an A-slab get the same blockIdx%8 -> same XCD -> A staged
// from HBM once, served from that XCD's L2 for the other 7.
// XOR swizzle (0-conflict, proven r5/r6): row r logical chunk c at phys c^(r&7).
// Epilogue: nb 0-3 -> rx = bf16(sigmoid(acc)*x); nb 4-7 -> z = bf16(sigmoid(acc-bg)).
__global__ __launch_bounds__(256, 4) void gemm_rz1(
    const u16* __restrict__ yb, const u16* __restrict__ xb,
    const u16* __restrict__ bRZ, const float* __restrict__ bg,
    u16* __restrict__ rxb, u16* __restrict__ zb) {
  __shared__ u16 smem[16384];  // sA 8192 | sB 8192 (u16), 32 KB
  u16* sA = smem;
  u16* sB = smem + 8192;

  const int tid = threadIdx.x;
  const int lane = tid & 63;
  const int wave = tid >> 6;
  const int waveM = wave >> 1, waveN = wave & 1;
  const int mb = blockIdx.x & 127, nb = blockIdx.x >> 7;  // mb fast -> A-sharers same XCD
  const int rowStart = mb * 128, colStart = nb * 128;
  const int wbyte = (tid & 192) * 16;
  const int lm = lane & 15, quad = lane >> 4;

  const int srow = tid >> 3;                              // 0..31 per slab
  const int scol = (((tid & 7) ^ ((tid >> 3) & 7)) * 8);  // logical chunk * 8 elems
  const int lswz = lm & 7;

  f32x4 acc[4][4] = {};

  for (int kq = 0; kq < 16; ++kq) {
    const int half = kq >> 3;
    const int k0 = (kq & 7) * 64;
    const u16* abase = half ? xb : yb;  // A = [y | x] along K
#pragma unroll
    for (int s = 0; s < 4; ++s) {
      async16(abase + (size_t)(rowStart + s * 32 + srow) * 512 + k0 + scol,
              (u16*)((char*)sA + s * 4096 + wbyte));
      async16(bRZ + (size_t)(colStart + s * 32 + srow) * 1024 + kq * 64 + scol,
              (u16*)((char*)sB + s * 4096 + wbyte));
    }
    __syncthreads();

#pragma unroll
    for (int kk = 0; kk < 2; ++kk) {
      bf16x8 aa[4], bw[4];
#pragma unroll
      for (int i = 0; i < 4; ++i)
        aa[i] = *(const bf16x8*)(sA + (waveM * 64 + i * 16 + lm) * 64 +
                                 ((kk * 4 + quad) ^ lswz) * 8);
#pragma unroll
      for (int j = 0; j < 4; ++j)
        bw[j] = *(const bf16x8*)(sB + (waveN * 64 + j * 16 + lm) * 64 +
                                 ((kk * 4 + quad) ^ lswz) * 8);
#pragma unroll
      for (int i = 0; i < 4; ++i)
#pragma unroll
        for (int j = 0; j < 4; ++j)
          acc[i][j] = __builtin_amdgcn_mfma_f32_16x16x32_bf16(aa[i], bw[j], acc[i][j], 0, 0, 0);
    }
    __syncthreads();
  }

  if (colStart < 512) {
    // R half: rx = bf16(sigmoid(acc) * x)
#pragma unroll
    for (int j = 0; j < 4; ++j) {
      const int e = colStart + waveN * 64 + j * 16 + lm;
#pragma unroll
      for (int i = 0; i < 4; ++i) {
        const int m0 = rowStart + waveM * 64 + i * 16 + quad * 4;
#pragma unroll
        for (int rg = 0; rg < 4; ++rg) {
          const size_t idx = (size_t)(m0 + rg) * 512 + e;
          const float r = sigmoidf_(acc[i][j][rg]);
          rxb[idx] = f2bf(r * bf2f(xb[idx]));
        }
      }
    }
  } else {
    // Z half: z = bf16(sigmoid(acc - bg))
#pragma unroll
    for (int j = 0; j < 4; ++j) {
      const int e = colStart - 512 + waveN * 64 + j * 16 + lm;
      const float bgv = bg[e];
#pragma unroll
      for (int i = 0; i < 4; ++i) {
        const int m0 = rowStart + waveM * 64 + i * 16 + quad * 4;
#pragma unroll
        for (int rg = 0; rg < 4; ++rg) {
          const size_t idx = (size_t)(m0 + rg) * 512 + e;
          zb[idx] = f2bf(sigmoidf_(acc[i][j][rg] - bgv));
        }
      }
    }
  }
}

// ---------- GEMM 2: accF = [y|rx] @ bG^T (M=16384, N=512, K=1024) ----------
// Same 128x128/BK=64 structure, grid 512, mb fast (same XCD trick: 128%8==0).
// Epilogue: out = (1-z)x + z*tanh(accF)
__global__ __launch_bounds__(256, 4) void gemm_gu1(
    const u16* __restrict__ yb, const u16* __restrict__ rxb,
    const u16* __restrict__ bG,
    const u16* __restrict__ zb, const u16* __restrict__ xb,
    float* __restrict__ out) {
  __shared__ u16 smem[16384];
  u16* sA = smem;
  u16* sB = smem + 8192;

  const int tid = threadIdx.x;
  const int lane = tid & 63;
  const int wave = tid >> 6;
  const int waveM = wave >> 1, waveN = wave & 1;
  const int mb = blockIdx.x & 127, nb = blockIdx.x >> 7;  // mb fast -> A-sharers same XCD
  const int rowStart = mb * 128, colStart = nb * 128;
  const int wbyte = (tid & 192) * 16;
  const int lm = lane & 15, quad = lane >> 4;

  const int srow = tid >> 3;
  const int scol = (((tid & 7) ^ ((tid >> 3) & 7)) * 8);
  const int lswz = lm & 7;

  f32x4 acc[4][4] = {};

  for (int kq = 0; kq < 16; ++kq) {
    const int half = kq >> 3;
    const int k0 = (kq & 7) * 64;
    const u16* abase = half ? rxb : yb;  // A = [y | rx] along K
#pragma unroll
    for (int s = 0; s < 4; ++s) {
      async16(abase + (size_t)(rowStart + s * 32 + srow) * 512 + k0 + scol,
              (u16*)((char*)sA + s * 4096 + wbyte));
      async16(bG + (size_t)(colStart + s * 32 + srow) * 1024 + kq * 64 + scol,
              (u16*)((char*)sB + s * 4096 + wbyte));
    }
    __syncthreads();

#pragma unroll
    for (int kk = 0; kk < 2; ++kk) {
      bf16x8 aa[4], bw[4];
#pragma unroll
      for (int i = 0; i < 4; ++i)
        aa[i] = *(const bf16x8*)(sA + (waveM * 64 + i * 16 + lm) * 64 +
                                 ((kk * 4 + quad) ^ lswz) * 8);
#pragma unroll
      for (int j = 0; j < 4; ++j)
        bw[j] = *(const bf16x8*)(sB + (waveN * 64 + j * 16 + lm) * 64 +
                                 ((kk * 4 + quad) ^ lswz) * 8);
#pragma unroll
      for (int i = 0; i < 4; ++i)
#pragma unroll
        for (int j = 0; j < 4; ++j)
          acc[i][j] = __builtin_amdgcn_mfma_f32_16x16x32_bf16(aa[i], bw[j], acc[i][j], 0, 0, 0);
    }
    __syncthreads();
  }

  // epilogue: out = (1-z)x + z*tanh(accF)
#pragma unroll
  for (int j = 0; j < 4; ++j) {
    const int e = colStart + waveN * 64 + j * 16 + lm;
#pragma unroll
    for (int i = 0; i < 4; ++i) {
      const int m0 = rowStart + waveM * 64 + i * 16 + quad * 4;
#pragma unroll
      for (int rg = 0; rg < 4; ++rg) {
        const size_t idx = (size_t)(m0 + rg) * 512 + e;
        const float pre = acc[i][j][rg];
        const float ex = __expf(-2.f * pre);
        const float h = (1.f - ex) / (1.f + ex);  // tanh
        const float z = bf2f(zb[idx]);
        const float xv = bf2f(xb[idx]);
        out[idx] = (1.f - z) * xv + z * h;
      }
    }
  }
}

// ---------- launch ----------
extern "C" void kernel_launch(void* const* d_in, const int* in_sizes, int n_in,
                              void* d_out, int out_size, void* d_ws, size_t ws_size,
                              hipStream_t stream) {
  const float* x  = (const float*)d_in[0];
  const float* y  = (const float*)d_in[1];
  const float* Wr = (const float*)d_in[2];
  const float* Ur = (const float*)d_in[3];
  const float* Wz = (const float*)d_in[4];
  const float* Uz = (const float*)d_in[5];
  const float* Wg = (const float*)d_in[6];
  const float* Ug = (const float*)d_in[7];
  const float* bg = (const float*)d_in[8];
  float* out = (float*)d_out;

  // ws layout (bytes): yb 16M | xb 16M | rxb 16M | zb 16M | bRZ 2M | bG 1M = 67 MB
  char* ws = (char*)d_ws;
  u16* yb  = (u16*)(ws);
  u16* xb  = (u16*)(ws + 16777216);
  u16* rxb = (u16*)(ws + 2 * 16777216);
  u16* zb  = (u16*)(ws + 3 * 16777216);
  u16* bRZ = (u16*)(ws + 4 * 16777216);
  u16* bG  = (u16*)(ws + 4 * 16777216 + 2097152);

  cast_all<<<17920, 256, 0, stream>>>(y, x, Wr, Ur, Wz, Uz, Wg, Ug, yb, xb, bRZ, bG);
  gemm_rz1<<<1024, 256, 0, stream>>>(yb, xb, bRZ, bg, rxb, zb);
  gemm_gu1<<<512, 256, 0, stream>>>(yb, rxb, bG, zb, xb, out);
}